// Round 3
// baseline (433.605 us; speedup 1.0000x reference)
//
#include <hip/hip_runtime.h>

// NLWT: 2x2 im2col -> M1 (4x4) -> roll subbands (s1: row -1, s2: col -1,
// s3: both -1, circular) -> M2 (4x4) -> out[b, s*C + c, i, j].
// Fused single-pass gather. Each thread computes FOUR output cols (j..j+3)
// for all 4 subbands of one (b,c) image:
//   loads 4 rows x (float4 + float4 + float2) = 40 B/row (32 B unique),
//   stores 4 x float4 (16 B/lane, the coalescing sweet spot).
// Stores are nontemporal: output is never re-read, keep it out of L2/L3 so
// the input wrap-row reuse stays cached. All fp32; M1/M2 as literals.

#define H  512
#define W  512
#define H1 256
#define W1 256

// Native clang vector type: __builtin_nontemporal_store requires a pointer
// to scalar or ext_vector, NOT HIP_vector_type<float,4>.
typedef float fx4 __attribute__((ext_vector_type(4)));

#define DOT(m0, m1, m2, m3, q, r, s, t) \
    fmaf((m0), (q), fmaf((m1), (r), fmaf((m2), (s), (m3) * (t))))

__global__ __launch_bounds__(256) void nlwt_kernel(const float* __restrict__ x,
                                                   float* __restrict__ out) {
    const int bc  = blockIdx.y;                       // image index: b*32 + c
    const int pid = (blockIdx.x << 8) + threadIdx.x;  // 0..16383 quad id
    const int i   = pid >> 6;                         // output row 0..255
    const int q   = pid & 63;                         // col-quad 0..63
    const int j   = q << 2;                           // output col base
    const int c0  = q << 3;                           // input col base (2*j)
    const int c8  = (c0 + 8) & (W - 1);               // wrapped +8 col

    const int r0 = i << 1;
    const int r2 = (r0 + 2) & (H - 1);                // wrapped next block row

    const float* img = x + (size_t)bc * (H * W);
    const float* p0  = img + r0 * W;
    const float* p1  = p0 + W;
    const float* p2  = img + r2 * W;
    const float* p3  = p2 + W;

    const float4 A0 = *(const float4*)(p0 + c0);
    const float4 B0 = *(const float4*)(p0 + c0 + 4);
    const float2 E0 = *(const float2*)(p0 + c8);
    const float4 A1 = *(const float4*)(p1 + c0);
    const float4 B1 = *(const float4*)(p1 + c0 + 4);
    const float2 E1 = *(const float2*)(p1 + c8);
    const float4 A2 = *(const float4*)(p2 + c0);
    const float4 B2 = *(const float4*)(p2 + c0 + 4);
    const float2 E2 = *(const float2*)(p2 + c8);
    const float4 A3 = *(const float4*)(p3 + c0);
    const float4 B3 = *(const float4*)(p3 + c0 + 4);
    const float2 E3 = *(const float2*)(p3 + c8);

    // Row views: 10 consecutive input cols per row (indices fold at compile
    // time after full unroll -> stays in registers, no scratch).
    const float v0[10] = {A0.x, A0.y, A0.z, A0.w, B0.x, B0.y, B0.z, B0.w, E0.x, E0.y};
    const float v1[10] = {A1.x, A1.y, A1.z, A1.w, B1.x, B1.y, B1.z, B1.w, E1.x, E1.y};
    const float v2[10] = {A2.x, A2.y, A2.z, A2.w, B2.x, B2.y, B2.z, B2.w, E2.x, E2.y};
    const float v3[10] = {A3.x, A3.y, A3.z, A3.w, B3.x, B3.y, B3.z, B3.w, E3.x, E3.y};

    // After-roll x1r for output pixel (i, j+k):
    //   t0 = M1.row0 . block(i,   j+k)    (cols 2k,2k+1 of rows p0,p1)
    //   t1 = M1.row1 . block(i+1, j+k)    (rows p2,p3)
    //   t2 = M1.row2 . block(i,   j+k+1)  (cols 2k+2,2k+3)
    //   t3 = M1.row3 . block(i+1, j+k+1)
    float o0[4], o1[4], o2[4], o3[4];
#pragma unroll
    for (int k = 0; k < 4; ++k) {
        const float t0 = DOT( 0.8664f,  0.1026f,  0.4852f, -0.0574f,
                              v0[2*k],   v0[2*k+1], v1[2*k],   v1[2*k+1]);
        const float t1 = DOT(-0.1026f,  0.8664f, -0.0574f, -0.4852f,
                              v2[2*k],   v2[2*k+1], v3[2*k],   v3[2*k+1]);
        const float t2 = DOT( 0.4852f,  0.0574f, -0.8664f,  0.1026f,
                              v0[2*k+2], v0[2*k+3], v1[2*k+2], v1[2*k+3]);
        const float t3 = DOT( 0.0574f, -0.4852f, -0.1026f, -0.8664f,
                              v2[2*k+2], v2[2*k+3], v3[2*k+2], v3[2*k+3]);

        o0[k] = DOT( 1.3968f,  0.2212f, -0.2212f, -1.3968f, t0, t1, t2, t3);
        o1[k] = DOT(-0.2212f,  1.3968f, -1.3968f,  0.2212f, t0, t1, t2, t3);
        o2[k] = DOT(-0.5412f, -1.3066f, -1.3066f, -0.5412f, t0, t1, t2, t3);
        o3[k] = DOT( 1.3066f, -0.5412f, -0.5412f,  1.3066f, t0, t1, t2, t3);
    }

    const int b  = bc >> 5;   // batch
    const int ch = bc & 31;   // channel
    float* obase = out + ((size_t)(b * 128 + ch) * (H1 * W1)) + i * W1 + j;
    const size_t sstride = (size_t)32 * H1 * W1;  // subband stride in channels

    const fx4 s0 = {o0[0], o0[1], o0[2], o0[3]};
    const fx4 s1 = {o1[0], o1[1], o1[2], o1[3]};
    const fx4 s2 = {o2[0], o2[1], o2[2], o2[3]};
    const fx4 s3 = {o3[0], o3[1], o3[2], o3[3]};
    __builtin_nontemporal_store(s0, (fx4*)(obase));
    __builtin_nontemporal_store(s1, (fx4*)(obase + sstride));
    __builtin_nontemporal_store(s2, (fx4*)(obase + 2 * sstride));
    __builtin_nontemporal_store(s3, (fx4*)(obase + 3 * sstride));
}

extern "C" void kernel_launch(void* const* d_in, const int* in_sizes, int n_in,
                              void* d_out, int out_size, void* d_ws, size_t ws_size,
                              hipStream_t stream) {
    const float* x = (const float*)d_in[0];
    float* out = (float*)d_out;
    // 256 images (b*c), each 256x256 outputs = 16384 col-quads -> 64 blocks/image
    dim3 grid(64, 256);
    nlwt_kernel<<<grid, 256, 0, stream>>>(x, out);
}

// Round 4
// 422.138 us; speedup vs baseline: 1.0272x; 1.0272x over previous
//
#include <hip/hip_runtime.h>

// NLWT: 2x2 im2col -> M1 (4x4) -> roll subbands (s1: row -1, s2: col -1,
// s3: both -1, circular) -> M2 (4x4) -> out[b, s*C + c, i, j].
// Fused single-pass gather: output pixel (i,j) needs input 2x2 blocks at
// (i,j), (i+1,j), (i,j+1), (i+1,j+1) (wrapped) = input rows 2i..2i+3,
// cols 2j..2j+5. Each thread computes TWO output cols (j, j+1) for all 4
// subbands of one (b,c) image: 4 rows x (float4 + float2) loads, 4 float2
// stores. All fp32 math; M1/M2 folded as compile-time literals.
//
// Round-3 post-mortem: 4-col threads (32B-lane-strided float4 loads) + nt
// stores regressed ~10 us — strided loads double L1/TA transactions per
// useful byte. This dense-load 2-col version is the measured best
// (420.7/423.7 us graded; kernel ~93 us = 92% of 6.29 TB/s achievable on
// 537 MB irreducible traffic).

#define H  512
#define W  512
#define H1 256
#define W1 256

#define DOT(m0, m1, m2, m3, q, r, s, t) \
    fmaf((m0), (q), fmaf((m1), (r), fmaf((m2), (s), (m3) * (t))))

__global__ __launch_bounds__(256) void nlwt_kernel(const float* __restrict__ x,
                                                   float* __restrict__ out) {
    const int bc  = blockIdx.y;                       // image index: b*32 + c
    const int pid = (blockIdx.x << 8) + threadIdx.x;  // 0..32767 pixel-pair id
    const int i   = pid >> 7;                         // output row 0..255
    const int jp  = pid & 127;                        // output col-pair 0..127
    const int c0  = jp << 2;                          // input col base (2*j)
    const int j   = jp << 1;                          // output col base

    const int r0 = i << 1;
    const int r2 = (r0 + 2) & (H - 1);                // wrapped next block row
    const int c4 = (c0 + 4) & (W - 1);                // wrapped next block col

    const float* img = x + (size_t)bc * (H * W);
    const float* p0  = img + r0 * W;
    const float* p1  = p0 + W;
    const float* p2  = img + r2 * W;
    const float* p3  = p2 + W;

    const float4 a0 = *(const float4*)(p0 + c0);
    const float2 e0 = *(const float2*)(p0 + c4);
    const float4 a1 = *(const float4*)(p1 + c0);
    const float2 e1 = *(const float2*)(p1 + c4);
    const float4 a2 = *(const float4*)(p2 + c0);
    const float2 e2 = *(const float2*)(p2 + c4);
    const float4 a3 = *(const float4*)(p3 + c0);
    const float2 e3 = *(const float2*)(p3 + c4);

    // Patch vector at block (bi,bj): [x(2bi,2bj), x(2bi,2bj+1), x(2bi+1,2bj), x(2bi+1,2bj+1)]
    // Block (i,j)   = a0.x a0.y a1.x a1.y
    // Block (i,j+1) = a0.z a0.w a1.z a1.w
    // Block (i,j+2) = e0.x e0.y e1.x e1.y
    // Block (i+1,*) = same with a2/a3/e2/e3
    //
    // After-roll x1r for output pixel (i,j):
    //   t0 = M1.row0 . block(i,  j)
    //   t1 = M1.row1 . block(i+1,j)
    //   t2 = M1.row2 . block(i,  j+1)
    //   t3 = M1.row3 . block(i+1,j+1)
    const float t0 = DOT( 0.8664f,  0.1026f,  0.4852f, -0.0574f, a0.x, a0.y, a1.x, a1.y);
    const float t1 = DOT(-0.1026f,  0.8664f, -0.0574f, -0.4852f, a2.x, a2.y, a3.x, a3.y);
    const float t2 = DOT( 0.4852f,  0.0574f, -0.8664f,  0.1026f, a0.z, a0.w, a1.z, a1.w);
    const float t3 = DOT( 0.0574f, -0.4852f, -0.1026f, -0.8664f, a2.z, a2.w, a3.z, a3.w);

    // output pixel (i, j+1): same with blocks shifted one to the right
    const float u0 = DOT( 0.8664f,  0.1026f,  0.4852f, -0.0574f, a0.z, a0.w, a1.z, a1.w);
    const float u1 = DOT(-0.1026f,  0.8664f, -0.0574f, -0.4852f, a2.z, a2.w, a3.z, a3.w);
    const float u2 = DOT( 0.4852f,  0.0574f, -0.8664f,  0.1026f, e0.x, e0.y, e1.x, e1.y);
    const float u3 = DOT( 0.0574f, -0.4852f, -0.1026f, -0.8664f, e2.x, e2.y, e3.x, e3.y);

    const int b  = bc >> 5;   // batch
    const int ch = bc & 31;   // channel
    float* obase = out + ((size_t)(b * 128 + ch) * (H1 * W1)) + i * W1 + j;
    const size_t sstride = (size_t)32 * H1 * W1;  // subband stride in channels

    float2 o;
    o.x = DOT( 1.3968f,  0.2212f, -0.2212f, -1.3968f, t0, t1, t2, t3);
    o.y = DOT( 1.3968f,  0.2212f, -0.2212f, -1.3968f, u0, u1, u2, u3);
    *(float2*)(obase) = o;
    o.x = DOT(-0.2212f,  1.3968f, -1.3968f,  0.2212f, t0, t1, t2, t3);
    o.y = DOT(-0.2212f,  1.3968f, -1.3968f,  0.2212f, u0, u1, u2, u3);
    *(float2*)(obase + sstride) = o;
    o.x = DOT(-0.5412f, -1.3066f, -1.3066f, -0.5412f, t0, t1, t2, t3);
    o.y = DOT(-0.5412f, -1.3066f, -1.3066f, -0.5412f, u0, u1, u2, u3);
    *(float2*)(obase + 2 * sstride) = o;
    o.x = DOT( 1.3066f, -0.5412f, -0.5412f,  1.3066f, t0, t1, t2, t3);
    o.y = DOT( 1.3066f, -0.5412f, -0.5412f,  1.3066f, u0, u1, u2, u3);
    *(float2*)(obase + 3 * sstride) = o;
}

extern "C" void kernel_launch(void* const* d_in, const int* in_sizes, int n_in,
                              void* d_out, int out_size, void* d_ws, size_t ws_size,
                              hipStream_t stream) {
    const float* x = (const float*)d_in[0];
    float* out = (float*)d_out;
    // 256 images (b*c), each 256x256 outputs = 32768 col-pairs -> 128 blocks/image
    dim3 grid(128, 256);
    nlwt_kernel<<<grid, 256, 0, stream>>>(x, out);
}